// Round 5
// baseline (676.610 us; speedup 1.0000x reference)
//
#include <hip/hip_runtime.h>
#include <hip/hip_cooperative_groups.h>

namespace cg = cooperative_groups;

#define B_  4
#define C_  16
#define H_  256
#define W_  256
#define CO_ 16
#define KS_ 3
#define KK_ 9
#define HW_ (H_ * W_)
// ws layout (u32 words): bf16 NHWC image | kbuf B-frags | partials (float)
#define IMG_WORDS ((size_t)B_ * HW_ * 8)   // 32 B per pixel
#define KER_OFF   IMG_WORDS
#define NKB 5                               // k-blocks per group: K=160
#define NBLK 2048                           // blocks: 128 pixels each
#define PART_OFF (KER_OFF + (size_t)NKB * 256)

typedef __attribute__((ext_vector_type(8))) short bf16x8;
typedef __attribute__((ext_vector_type(4))) float f32x4;
union U4S8 { uint4 u; bf16x8 s; };

#define LOBF(u) __uint_as_float((u) << 16)
#define HIBF(u) __uint_as_float((u) & 0xffff0000u)

__device__ __forceinline__ unsigned rne_bf16(float v) {
    unsigned b = __float_as_uint(v);
    return (b + 0x7fffu + ((b >> 16) & 1u)) >> 16;
}

// ------- tap address/weight setup ------------------------------------------
__device__ __forceinline__ void tap_setup(
    int h, int w, int kk, float dy, float dx,
    int* idx, float* wt)
{
    const float y = dy + (float)(h - 1 + kk / KS_);
    const float x = dx + (float)(w - 1 + kk % KS_);
    const float y0f = floorf(y);
    const float x0f = floorf(x);
    const int   y0  = (int)y0f;
    const int   x0  = (int)x0f;
    const float wy  = y - y0f;
    const float wx  = x - x0f;

    float w00 = (1.f - wy) * (1.f - wx);
    float w01 = (1.f - wy) * wx;
    float w10 = wy * (1.f - wx);
    float w11 = wy * wx;

    const bool v0y = ((unsigned)y0       < (unsigned)H_);
    const bool v1y = ((unsigned)(y0 + 1) < (unsigned)H_);
    const bool v0x = ((unsigned)x0       < (unsigned)W_);
    const bool v1x = ((unsigned)(x0 + 1) < (unsigned)W_);

    wt[0] = (v0y & v0x) ? w00 : 0.f;
    wt[1] = (v0y & v1x) ? w01 : 0.f;
    wt[2] = (v1y & v0x) ? w10 : 0.f;
    wt[3] = (v1y & v1x) ? w11 : 0.f;

    const int y0c = min(max(y0,     0), H_ - 1);
    const int y1c = min(max(y0 + 1, 0), H_ - 1);
    const int x0c = min(max(x0,     0), W_ - 1);
    const int x1c = min(max(x0 + 1, 0), W_ - 1);

    idx[0] = y0c * W_ + x0c;
    idx[1] = y0c * W_ + x1c;
    idx[2] = y1c * W_ + x0c;
    idx[3] = y1c * W_ + x1c;
}

// blend + truncation-pack to bf16 pair: two independent scalar fma chains
// + one v_perm_b32 (the f32x2/v_pk_fma variant regressed: VOP3P needs
// aligned VGPR pairs -> 8 marshalling movs per call).
__device__ __forceinline__ unsigned blendpack(
    unsigned a, unsigned b, unsigned c, unsigned d,
    float w0, float w1, float w2, float w3)
{
    const float lo = w0 * LOBF(a) + w1 * LOBF(b) + w2 * LOBF(c) + w3 * LOBF(d);
    const float hi = w0 * HIBF(a) + w1 * HIBF(b) + w2 * HIBF(c) + w3 * HIBF(d);
    // result = [hi:31-16 | lo:31-16]  (bytes a3,a2,b3,b2)
    return __builtin_amdgcn_perm(__float_as_uint(hi), __float_as_uint(lo),
                                 0x07060302u);
}

// ------- Fused cooperative kernel: pack -> sync -> deform -> sync -> reduce
// __launch_bounds__(256, 8): 8 blocks/CU * 256 CUs = 2048 co-resident blocks
// (caps VGPR at 64 — the deform loop already fits exactly). Saves two
// dispatch ramps/gaps vs the 3-kernel structure.
__global__ __launch_bounds__(256, 8) void fused_deform(
    const float* __restrict__ off, const float* __restrict__ inp,
    const float* __restrict__ ker, const float* __restrict__ tgt,
    unsigned* __restrict__ wsu, float* __restrict__ partials,
    float* __restrict__ out)
{
    cg::grid_group grid = cg::this_grid();

    const int bx = blockIdx.x;
    // XCD swizzle: bijection on [0,2048); xcd = bx&7 covers 256 consecutive
    // 128-pixel blocks = 128 contiguous rows -> per-XCD L2 locality.
    // Phase A packs the SAME 128-px stripe this block deforms in phase B,
    // so the bf16 records are dirty in the LOCAL per-XCD L2.
    const int f = (bx & 7) * 256 + (bx >> 3);
    const int t = threadIdx.x;

    // ---- Phase A: pack this block's 128 pixels (NCHW fp32 -> NHWC bf16) --
    {
        const int half = t >> 7;            // 0: c0-7, 1: c8-15
        const int p    = t & 127;
        const int e    = f * 128 + p;       // flat pixel
        const int b    = e >> 16;
        const int hw   = e & (HW_ - 1);
        const float* src = inp + (size_t)b * (C_ * HW_)
                         + (size_t)(half * 8) * HW_ + hw;
        float v[8];
#pragma unroll
        for (int c = 0; c < 8; c++)
            v[c] = src[c * HW_];            // coalesced per c-plane
        unsigned u[4];
#pragma unroll
        for (int j = 0; j < 4; j++)
            u[j] = rne_bf16(v[2 * j]) | (rne_bf16(v[2 * j + 1]) << 16);
        ((uint4*)wsu)[(size_t)e * 2 + half] = make_uint4(u[0], u[1], u[2], u[3]);
    }
    if (bx == 0) {
        // kbuf: B-fragment layout for mfma_f32_16x16x32_bf16.
        //   B[k][n]: k = (lane>>4)*8 + j, n = o = lane&15,
        //   tap = 2*blk + (k>>4), c = k&15; zero when tap > 8 (K padding).
        for (int i = t; i < NKB * 256; i += 256) {
            const int wj  = i & 3;
            const int l   = (i >> 2) & 63;
            const int blk = i >> 8;
            const int o   = l & 15;
            unsigned lo = 0, hi = 0;
            {
                int jj = 2 * wj, k = (l >> 4) * 8 + jj;
                int tap = 2 * blk + (k >> 4), c = k & 15;
                if (tap <= 8) lo = rne_bf16(ker[(o * C_ + c) * KK_ + tap]);
                jj = 2 * wj + 1; k = (l >> 4) * 8 + jj;
                tap = 2 * blk + (k >> 4); c = k & 15;
                if (tap <= 8) hi = rne_bf16(ker[(o * C_ + c) * KK_ + tap]);
            }
            wsu[KER_OFF + i] = lo | (hi << 16);
        }
    }

    grid.sync();   // all packing device-visible before any gather

    // ---- Phase B: deform-conv + MSE via MFMA (identical to 3-kernel ver) -
    const int l = t & 63;
    const int q = l >> 4;
    const int m = l & 15;
    const int base = f * 128 + (t >> 6) * 32;   // wave's 32-pixel span
    const int b    = base >> 16;                // span never crosses b
    const int hwb  = base & (HW_ - 1);
    const int h    = hwb >> 8;                  // same row for both groups
    const int w0   = (hwb & (W_ - 1)) + m;      // group g pixel w = w0+16g

    const float* offp = off + (size_t)b * (2 * KK_ * HW_) + (size_t)h * W_;
    const uint4* ib   = ((const uint4*)wsu) + (size_t)b * HW_ * 2;
    const uint4* kb   = (const uint4*)(wsu + KER_OFF);

    // B-fragments: 5 x 16 B, register-resident
    bf16x8 bfr[NKB];
#pragma unroll
    for (int kbk = 0; kbk < NKB; kbk++) {
        U4S8 cv; cv.u = kb[kbk * 64 + l];
        bfr[kbk] = cv.s;
    }

    // ALL entry loads issued together: 20 offsets + 2 target float4s.
    // tap>8 clamped to 8: valid memory; contribution zeroed by B=0 padding.
    float dyv[2][NKB], dxv[2][NKB];
#pragma unroll
    for (int g = 0; g < 2; g++)
#pragma unroll
        for (int kbk = 0; kbk < NKB; kbk++) {
            const int tap = min(2 * kbk + (q >> 1), KK_ - 1);
            dyv[g][kbk] = offp[(size_t)(2 * tap) * HW_ + w0 + 16 * g];
            dxv[g][kbk] = offp[(size_t)(2 * tap + 1) * HW_ + w0 + 16 * g];
        }
    // targets (C/D layout: col=lane&15=o, row=4q+reg=pixel-in-group)
    const float* tbase = tgt + (size_t)b * (CO_ * HW_) + (size_t)m * HW_
                       + hwb + 4 * q;
    const float4 tv0 = *(const float4*)(tbase);
    const float4 tv1 = *(const float4*)(tbase + 16);

    f32x4 acc[2] = {{0.f, 0.f, 0.f, 0.f}, {0.f, 0.f, 0.f, 0.f}};
    uint4 cor[2][4];
    float wts[2][4];

    // prologue: group 0, k-block 0 (never a padding block)
    {
        int idx[4];
        tap_setup(h, w0, q >> 1, dyv[0][0], dxv[0][0], idx, wts[0]);
#pragma unroll
        for (int i = 0; i < 4; i++) cor[0][i] = ib[idx[i] * 2 + (q & 1)];
    }

#pragma unroll
    for (int kbi = 0; kbi < 2 * NKB; kbi++) {
        const int cur = kbi & 1, nxt = cur ^ 1;
        if (kbi + 1 < 2 * NKB) {
            const int gn = (kbi + 1) / NKB, kn = (kbi + 1) % NKB;
            int idx[4];
            tap_setup(h, w0 + 16 * gn, min(2 * kn + (q >> 1), KK_ - 1),
                      dyv[gn][kn], dxv[gn][kn], idx, wts[nxt]);
            if (kn == NKB - 1) {
                // K-padding lanes (tap 9): B-frag is 0 there, so collapse
                // their gathers onto record 0 (broadcast, 1-2 cachelines)
                // with wt=0 instead of scattering real clamped-tap-8 gathers.
                const bool pad = (q >> 1) != 0;
                if (pad) {
                    wts[nxt][0] = 0.f; wts[nxt][1] = 0.f;
                    wts[nxt][2] = 0.f; wts[nxt][3] = 0.f;
                    idx[0] = 0; idx[1] = 0; idx[2] = 0; idx[3] = 0;
                }
            }
#pragma unroll
            for (int i = 0; i < 4; i++) cor[nxt][i] = ib[idx[i] * 2 + (q & 1)];
        }

        const int g = kbi / NKB;
        const int kkb = kbi % NKB;
        const float w0_ = wts[cur][0], w1_ = wts[cur][1],
                    w2_ = wts[cur][2], w3_ = wts[cur][3];
        const uint4 c0 = cor[cur][0], c1 = cor[cur][1],
                    c2 = cor[cur][2], c3 = cor[cur][3];
        uint4 A4;
        A4.x = blendpack(c0.x, c1.x, c2.x, c3.x, w0_, w1_, w2_, w3_);
        A4.y = blendpack(c0.y, c1.y, c2.y, c3.y, w0_, w1_, w2_, w3_);
        A4.z = blendpack(c0.z, c1.z, c2.z, c3.z, w0_, w1_, w2_, w3_);
        A4.w = blendpack(c0.w, c1.w, c2.w, c3.w, w0_, w1_, w2_, w3_);
        U4S8 ca; ca.u = A4;

        acc[g] = __builtin_amdgcn_mfma_f32_16x16x32_bf16(ca.s, bfr[kkb],
                                                         acc[g], 0, 0, 0);
    }

    float d0 = acc[0][0] - tv0.x, d1 = acc[0][1] - tv0.y,
          d2 = acc[0][2] - tv0.z, d3 = acc[0][3] - tv0.w;
    float e0 = acc[1][0] - tv1.x, e1 = acc[1][1] - tv1.y,
          e2 = acc[1][2] - tv1.z, e3 = acc[1][3] - tv1.w;
    float part = (d0 * d0 + d1 * d1 + d2 * d2 + d3 * d3
                + e0 * e0 + e1 * e1 + e2 * e2 + e3 * e3)
               * (1.0f / (float)((size_t)B_ * CO_ * HW_));

    // wave reduce -> LDS -> ONE plain store per block (no atomics: 2048
    // same-address atomics serialize into a ~6 us burst tail — measured r2)
#pragma unroll
    for (int sft = 32; sft > 0; sft >>= 1)
        part += __shfl_down(part, sft, 64);

    __shared__ float red[4];
    if (l == 0)
        red[t >> 6] = part;
    __syncthreads();
    if (t == 0)
        partials[bx] = red[0] + red[1] + red[2] + red[3];

    grid.sync();   // all partials device-visible

    // ---- Phase C: block 0 reduces 2048 partials -> out -------------------
    if (bx == 0) {
        float s = 0.f;
#pragma unroll
        for (int i = 0; i < NBLK / 256; i++)
            s += partials[t + i * 256];
#pragma unroll
        for (int sft = 32; sft > 0; sft >>= 1)
            s += __shfl_down(s, sft, 64);
        if ((t & 63) == 0) red[t >> 6] = s;
        __syncthreads();
        if (t == 0) out[0] = red[0] + red[1] + red[2] + red[3];
    }
}

// ======= Fallback path: proven 3-kernel structure (round-4, 113.1 us) ======

__global__ __launch_bounds__(256) void pack_nhwc_bf16(
    const float* __restrict__ inp, const float* __restrict__ ker,
    unsigned* __restrict__ wsu)
{
    const int t = threadIdx.x;
    // bijection on [0,1024): XCD x=bx&7 covers 256-px chunks [x*128,(x+1)*128)
    const int j = (blockIdx.x & 7) * 128 + (blockIdx.x >> 3);
    const int e = j * 256 + t;              // flat pixel (b*HW + hw)
    const int b = e >> 16;
    const int hw = e & (HW_ - 1);
    const float* src = inp + (size_t)b * (C_ * HW_) + hw;
    float v[C_];
#pragma unroll
    for (int c = 0; c < C_; c++)
        v[c] = src[c * HW_];                // coalesced per c-plane
    unsigned u[8];
#pragma unroll
    for (int j2 = 0; j2 < 8; j2++)
        u[j2] = rne_bf16(v[2 * j2]) | (rne_bf16(v[2 * j2 + 1]) << 16);
    uint4* dst = ((uint4*)wsu) + (size_t)e * 2;   // 32 B per pixel
    dst[0] = make_uint4(u[0], u[1], u[2], u[3]);
    dst[1] = make_uint4(u[4], u[5], u[6], u[7]);

    if (blockIdx.x == 0) {
        for (int i = t; i < NKB * 256; i += 256) {
            const int wj  = i & 3;
            const int l   = (i >> 2) & 63;
            const int blk = i >> 8;
            const int o   = l & 15;
            unsigned lo = 0, hi = 0;
            {
                int jj = 2 * wj, k = (l >> 4) * 8 + jj;
                int tap = 2 * blk + (k >> 4), c = k & 15;
                if (tap <= 8) lo = rne_bf16(ker[(o * C_ + c) * KK_ + tap]);
                jj = 2 * wj + 1; k = (l >> 4) * 8 + jj;
                tap = 2 * blk + (k >> 4); c = k & 15;
                if (tap <= 8) hi = rne_bf16(ker[(o * C_ + c) * KK_ + tap]);
            }
            wsu[KER_OFF + i] = lo | (hi << 16);
        }
    }
}

__global__ __launch_bounds__(256) void deform_loss_mfma(
    const float* __restrict__ off, const unsigned* __restrict__ wsu,
    const float* __restrict__ tgt, float* __restrict__ partials)
{
    const int f = (blockIdx.x & 7) * 256 + (blockIdx.x >> 3);
    const int t = threadIdx.x;
    const int l = t & 63;
    const int q = l >> 4;
    const int m = l & 15;
    const int base = f * 128 + (t >> 6) * 32;
    const int b    = base >> 16;
    const int hwb  = base & (HW_ - 1);
    const int h    = hwb >> 8;
    const int w0   = (hwb & (W_ - 1)) + m;

    const float* offp = off + (size_t)b * (2 * KK_ * HW_) + (size_t)h * W_;
    const uint4* ib   = ((const uint4*)wsu) + (size_t)b * HW_ * 2;
    const uint4* kb   = (const uint4*)(wsu + KER_OFF);

    bf16x8 bfr[NKB];
#pragma unroll
    for (int kbk = 0; kbk < NKB; kbk++) {
        U4S8 cv; cv.u = kb[kbk * 64 + l];
        bfr[kbk] = cv.s;
    }

    float dyv[2][NKB], dxv[2][NKB];
#pragma unroll
    for (int g = 0; g < 2; g++)
#pragma unroll
        for (int kbk = 0; kbk < NKB; kbk++) {
            const int tap = min(2 * kbk + (q >> 1), KK_ - 1);
            dyv[g][kbk] = offp[(size_t)(2 * tap) * HW_ + w0 + 16 * g];
            dxv[g][kbk] = offp[(size_t)(2 * tap + 1) * HW_ + w0 + 16 * g];
        }
    const float* tbase = tgt + (size_t)b * (CO_ * HW_) + (size_t)m * HW_
                       + hwb + 4 * q;
    const float4 tv0 = *(const float4*)(tbase);
    const float4 tv1 = *(const float4*)(tbase + 16);

    f32x4 acc[2] = {{0.f, 0.f, 0.f, 0.f}, {0.f, 0.f, 0.f, 0.f}};
    uint4 cor[2][4];
    float wts[2][4];

    {
        int idx[4];
        tap_setup(h, w0, q >> 1, dyv[0][0], dxv[0][0], idx, wts[0]);
#pragma unroll
        for (int i = 0; i < 4; i++) cor[0][i] = ib[idx[i] * 2 + (q & 1)];
    }

#pragma unroll
    for (int kbi = 0; kbi < 2 * NKB; kbi++) {
        const int cur = kbi & 1, nxt = cur ^ 1;
        if (kbi + 1 < 2 * NKB) {
            const int gn = (kbi + 1) / NKB, kn = (kbi + 1) % NKB;
            int idx[4];
            tap_setup(h, w0 + 16 * gn, min(2 * kn + (q >> 1), KK_ - 1),
                      dyv[gn][kn], dxv[gn][kn], idx, wts[nxt]);
            if (kn == NKB - 1) {
                const bool pad = (q >> 1) != 0;
                if (pad) {
                    wts[nxt][0] = 0.f; wts[nxt][1] = 0.f;
                    wts[nxt][2] = 0.f; wts[nxt][3] = 0.f;
                    idx[0] = 0; idx[1] = 0; idx[2] = 0; idx[3] = 0;
                }
            }
#pragma unroll
            for (int i = 0; i < 4; i++) cor[nxt][i] = ib[idx[i] * 2 + (q & 1)];
        }

        const int g = kbi / NKB;
        const int kkb = kbi % NKB;
        const float w0_ = wts[cur][0], w1_ = wts[cur][1],
                    w2_ = wts[cur][2], w3_ = wts[cur][3];
        const uint4 c0 = cor[cur][0], c1 = cor[cur][1],
                    c2 = cor[cur][2], c3 = cor[cur][3];
        uint4 A4;
        A4.x = blendpack(c0.x, c1.x, c2.x, c3.x, w0_, w1_, w2_, w3_);
        A4.y = blendpack(c0.y, c1.y, c2.y, c3.y, w0_, w1_, w2_, w3_);
        A4.z = blendpack(c0.z, c1.z, c2.z, c3.z, w0_, w1_, w2_, w3_);
        A4.w = blendpack(c0.w, c1.w, c2.w, c3.w, w0_, w1_, w2_, w3_);
        U4S8 ca; ca.u = A4;

        acc[g] = __builtin_amdgcn_mfma_f32_16x16x32_bf16(ca.s, bfr[kkb],
                                                         acc[g], 0, 0, 0);
    }

    float d0 = acc[0][0] - tv0.x, d1 = acc[0][1] - tv0.y,
          d2 = acc[0][2] - tv0.z, d3 = acc[0][3] - tv0.w;
    float e0 = acc[1][0] - tv1.x, e1 = acc[1][1] - tv1.y,
          e2 = acc[1][2] - tv1.z, e3 = acc[1][3] - tv1.w;
    float part = (d0 * d0 + d1 * d1 + d2 * d2 + d3 * d3
                + e0 * e0 + e1 * e1 + e2 * e2 + e3 * e3)
               * (1.0f / (float)((size_t)B_ * CO_ * HW_));

#pragma unroll
    for (int sft = 32; sft > 0; sft >>= 1)
        part += __shfl_down(part, sft, 64);

    __shared__ float red[4];
    if (l == 0)
        red[t >> 6] = part;
    __syncthreads();
    if (t == 0)
        partials[blockIdx.x] = red[0] + red[1] + red[2] + red[3];
}

__global__ __launch_bounds__(256) void reduce_partials(
    const float* __restrict__ partials, float* __restrict__ out)
{
    const int t = threadIdx.x;
    float s = 0.f;
#pragma unroll
    for (int i = 0; i < NBLK / 256; i++)
        s += partials[t + i * 256];
#pragma unroll
    for (int sft = 32; sft > 0; sft >>= 1)
        s += __shfl_down(s, sft, 64);
    __shared__ float red[4];
    if ((t & 63) == 0) red[t >> 6] = s;
    __syncthreads();
    if (t == 0) out[0] = red[0] + red[1] + red[2] + red[3];
}

// ------- Fallback (round-1 NCHW kernel, used if ws too small) --------------
__global__ __launch_bounds__(256) void deform_loss_kernel(
    const float* __restrict__ off, const float* __restrict__ inp,
    const float* __restrict__ ker, const float* __restrict__ tgt,
    float* __restrict__ out)
{
    const int idx = blockIdx.x * blockDim.x + threadIdx.x;
    float part = 0.f;
    if (idx < B_ * H_ * W_) {
        const int w  = idx & (W_ - 1);
        const int h  = (idx >> 8) & (H_ - 1);
        const int b  = idx >> 16;
        const int hw = h * W_ + w;
        const float* offb = off + (size_t)b * (2 * KK_ * HW_);
        const float* inpb = inp + (size_t)b * (C_ * HW_);
        float acc[CO_];
#pragma unroll
        for (int o = 0; o < CO_; o++) acc[o] = 0.f;
        for (int kk = 0; kk < KK_; kk++) {
            const float dy = offb[(2 * kk)     * HW_ + hw];
            const float dx = offb[(2 * kk + 1) * HW_ + hw];
            const float y = dy + (float)(h - 1 + kk / KS_);
            const float x = dx + (float)(w - 1 + kk % KS_);
            const float y0f = floorf(y);
            const float x0f = floorf(x);
            const int   y0  = (int)y0f;
            const int   x0  = (int)x0f;
            const float wy  = y - y0f;
            const float wx  = x - x0f;
            float w00 = (1.f - wy) * (1.f - wx);
            float w01 = (1.f - wy) * wx;
            float w10 = wy * (1.f - wx);
            float w11 = wy * wx;
            const bool v0y = ((unsigned)y0       < (unsigned)H_);
            const bool v1y = ((unsigned)(y0 + 1) < (unsigned)H_);
            const bool v0x = ((unsigned)x0       < (unsigned)W_);
            const bool v1x = ((unsigned)(x0 + 1) < (unsigned)W_);
            w00 = (v0y & v0x) ? w00 : 0.f;
            w01 = (v0y & v1x) ? w01 : 0.f;
            w10 = (v1y & v0x) ? w10 : 0.f;
            w11 = (v1y & v1x) ? w11 : 0.f;
            const int i00 = min(max(y0,0),H_-1)*W_ + min(max(x0,0),W_-1);
            const int i01 = min(max(y0,0),H_-1)*W_ + min(max(x0+1,0),W_-1);
            const int i10 = min(max(y0+1,0),H_-1)*W_ + min(max(x0,0),W_-1);
            const int i11 = min(max(y0+1,0),H_-1)*W_ + min(max(x0+1,0),W_-1);
            for (int c = 0; c < C_; c++) {
                const float* pp = inpb + c * HW_;
                const float s = pp[i00]*w00 + pp[i01]*w01 + pp[i10]*w10 + pp[i11]*w11;
#pragma unroll
                for (int o = 0; o < CO_; o++)
                    acc[o] = fmaf(s, ker[(o * C_ + c) * KK_ + kk], acc[o]);
            }
        }
        const float* tb = tgt + (size_t)b * (CO_ * HW_);
#pragma unroll
        for (int o = 0; o < CO_; o++) {
            const float d = acc[o] - tb[o * HW_ + hw];
            part = fmaf(d, d, part);
        }
        part *= (1.0f / (float)((size_t)B_ * CO_ * HW_));
    }
#pragma unroll
    for (int sft = 32; sft > 0; sft >>= 1)
        part += __shfl_down(part, sft, 64);
    if ((threadIdx.x & 63) == 0)
        atomicAdd(out, part);
}

extern "C" void kernel_launch(void* const* d_in, const int* in_sizes, int n_in,
                              void* d_out, int out_size, void* d_ws, size_t ws_size,
                              hipStream_t stream) {
    const float* offsets = (const float*)d_in[0];
    const float* input   = (const float*)d_in[1];
    const float* ker     = (const float*)d_in[2];
    const float* target  = (const float*)d_in[3];
    float* out = (float*)d_out;

    const size_t need = (PART_OFF + NBLK) * sizeof(unsigned);
    if (ws_size >= need) {
        unsigned* wsu = (unsigned*)d_ws;
        float* pp = (float*)(wsu + PART_OFF);

        // single cooperative dispatch: pack -> sync -> deform -> sync -> red
        void* args[] = { (void*)&offsets, (void*)&input, (void*)&ker,
                         (void*)&target,  (void*)&wsu,   (void*)&pp,
                         (void*)&out };
        hipError_t err = hipLaunchCooperativeKernel(
            (void*)fused_deform, dim3(NBLK), dim3(256), args, 0, stream);
        if (err == hipSuccess) return;

        // fallback: proven 3-kernel structure (round 4, 113.1 us)
        pack_nhwc_bf16<<<(B_ * HW_) / 256, 256, 0, stream>>>(input, ker, wsu);
        deform_loss_mfma<<<NBLK, 256, 0, stream>>>(offsets, wsu, target, pp);
        reduce_partials<<<1, 256, 0, stream>>>(pp, out);
    } else {
        hipMemsetAsync(out, 0, sizeof(float), stream);
        const int total = B_ * H_ * W_;
        deform_loss_kernel<<<(total + 255) / 256, 256, 0, stream>>>(
            offsets, input, ker, target, out);
    }
}

// Round 6
// 118.486 us; speedup vs baseline: 5.7105x; 5.7105x over previous
//
#include <hip/hip_runtime.h>

#define B_  4
#define C_  16
#define H_  256
#define W_  256
#define CO_ 16
#define KS_ 3
#define KK_ 9
#define HW_ (H_ * W_)
// ws layout (u32 words): bf16 NHWC image | kbuf B-frags | partials (float)
#define IMG_WORDS ((size_t)B_ * HW_ * 8)   // 32 B per pixel
#define KER_OFF   IMG_WORDS
#define NKB 5                               // k-blocks per group: K=160
#define NBLK 2048                           // blocks: 128 pixels each
#define PART_OFF (KER_OFF + (size_t)NKB * 256)

typedef __attribute__((ext_vector_type(8))) short bf16x8;
typedef __attribute__((ext_vector_type(4))) float f32x4;
union U4S8 { uint4 u; bf16x8 s; };

#define LOBF(u) __uint_as_float((u) << 16)
#define HIBF(u) __uint_as_float((u) & 0xffff0000u)

__device__ __forceinline__ unsigned rne_bf16(float v) {
    unsigned b = __float_as_uint(v);
    return (b + 0x7fffu + ((b >> 16) & 1u)) >> 16;
}

// ------- Kernel 1: NCHW fp32 -> NHWC bf16 pack + B-fragment kernel pack ----
// Block mapping XCD-aligned with deform_loss_mfma: pack block bx (on XCD
// bx&7) writes exactly the pixel range that deform blocks on the same XCD
// will gather -> image stays dirty-resident in the LOCAL per-XCD L2.
// Input fp32 reads are read-once -> nontemporal (don't evict image lines).
__global__ __launch_bounds__(256) void pack_nhwc_bf16(
    const float* __restrict__ inp, const float* __restrict__ ker,
    unsigned* __restrict__ wsu)
{
    const int t = threadIdx.x;
    // bijection on [0,1024): XCD x=bx&7 covers 256-px chunks [x*128,(x+1)*128)
    const int j = (blockIdx.x & 7) * 128 + (blockIdx.x >> 3);
    const int e = j * 256 + t;              // flat pixel (b*HW + hw)
    const int b = e >> 16;
    const int hw = e & (HW_ - 1);
    const float* src = inp + (size_t)b * (C_ * HW_) + hw;
    float v[C_];
#pragma unroll
    for (int c = 0; c < C_; c++)
        v[c] = __builtin_nontemporal_load(&src[c * HW_]);   // coalesced, nt
    unsigned u[8];
#pragma unroll
    for (int j2 = 0; j2 < 8; j2++)
        u[j2] = rne_bf16(v[2 * j2]) | (rne_bf16(v[2 * j2 + 1]) << 16);
    uint4* dst = ((uint4*)wsu) + (size_t)e * 2;   // 32 B per pixel
    dst[0] = make_uint4(u[0], u[1], u[2], u[3]);  // normal store: L2-resident
    dst[1] = make_uint4(u[4], u[5], u[6], u[7]);

    if (blockIdx.x == 0) {
        // kbuf: B-fragment layout for mfma_f32_16x16x32_bf16.
        //   B[k][n]: k = (lane>>4)*8 + j, n = o = lane&15,
        //   tap = 2*blk + (k>>4), c = k&15; zero when tap > 8 (K padding).
        for (int i = t; i < NKB * 256; i += 256) {
            const int wj  = i & 3;
            const int l   = (i >> 2) & 63;
            const int blk = i >> 8;
            const int o   = l & 15;
            unsigned lo = 0, hi = 0;
            {
                int jj = 2 * wj, k = (l >> 4) * 8 + jj;
                int tap = 2 * blk + (k >> 4), c = k & 15;
                if (tap <= 8) lo = rne_bf16(ker[(o * C_ + c) * KK_ + tap]);
                jj = 2 * wj + 1; k = (l >> 4) * 8 + jj;
                tap = 2 * blk + (k >> 4); c = k & 15;
                if (tap <= 8) hi = rne_bf16(ker[(o * C_ + c) * KK_ + tap]);
            }
            wsu[KER_OFF + i] = lo | (hi << 16);
        }
    }
}

// ------- tap address/weight setup ------------------------------------------
__device__ __forceinline__ void tap_setup(
    int h, int w, int kk, float dy, float dx,
    int* idx, float* wt)
{
    const float y = dy + (float)(h - 1 + kk / KS_);
    const float x = dx + (float)(w - 1 + kk % KS_);
    const float y0f = floorf(y);
    const float x0f = floorf(x);
    const int   y0  = (int)y0f;
    const int   x0  = (int)x0f;
    const float wy  = y - y0f;
    const float wx  = x - x0f;

    float w00 = (1.f - wy) * (1.f - wx);
    float w01 = (1.f - wy) * wx;
    float w10 = wy * (1.f - wx);
    float w11 = wy * wx;

    const bool v0y = ((unsigned)y0       < (unsigned)H_);
    const bool v1y = ((unsigned)(y0 + 1) < (unsigned)H_);
    const bool v0x = ((unsigned)x0       < (unsigned)W_);
    const bool v1x = ((unsigned)(x0 + 1) < (unsigned)W_);

    wt[0] = (v0y & v0x) ? w00 : 0.f;
    wt[1] = (v0y & v1x) ? w01 : 0.f;
    wt[2] = (v1y & v0x) ? w10 : 0.f;
    wt[3] = (v1y & v1x) ? w11 : 0.f;

    const int y0c = min(max(y0,     0), H_ - 1);
    const int y1c = min(max(y0 + 1, 0), H_ - 1);
    const int x0c = min(max(x0,     0), W_ - 1);
    const int x1c = min(max(x0 + 1, 0), W_ - 1);

    idx[0] = y0c * W_ + x0c;
    idx[1] = y0c * W_ + x1c;
    idx[2] = y1c * W_ + x0c;
    idx[3] = y1c * W_ + x1c;
}

// blend + truncation-pack to bf16 pair: two independent scalar fma chains
// + one v_perm_b32 (the f32x2/v_pk_fma variant regressed: VOP3P needs
// aligned VGPR pairs -> 8 marshalling movs per call).
__device__ __forceinline__ unsigned blendpack(
    unsigned a, unsigned b, unsigned c, unsigned d,
    float w0, float w1, float w2, float w3)
{
    const float lo = w0 * LOBF(a) + w1 * LOBF(b) + w2 * LOBF(c) + w3 * LOBF(d);
    const float hi = w0 * HIBF(a) + w1 * HIBF(b) + w2 * HIBF(c) + w3 * HIBF(d);
    // result = [hi:31-16 | lo:31-16]  (bytes a3,a2,b3,b2)
    return __builtin_amdgcn_perm(__float_as_uint(hi), __float_as_uint(lo),
                                 0x07060302u);
}

// ------- Kernel 2: deform-conv + MSE via MFMA, 2 groups/wave, no atomics ---
// Wave = 2 groups x 16 pixels x 4 k-quads. Lane(q=l>>4, m=l&15) holds
// k = q*8+j -> one 16B half of a bf16 NHWC record. 5 MFMAs per group.
// Stream-once data (offsets, targets) loaded NONTEMPORAL so the per-XCD L2
// keeps the packed image resident for the bilinear gathers (the ~4.5 MB/XCD
// offset+target stream otherwise LRU-evicts the 1 MB image slice).
__global__ __launch_bounds__(256) void deform_loss_mfma(
    const float* __restrict__ off, const unsigned* __restrict__ wsu,
    const float* __restrict__ tgt, float* __restrict__ partials)
{
    // XCD swizzle: bijection on [0,2048); xcd = blk&7 covers 256 consecutive
    // 128-pixel blocks = 128 contiguous rows -> per-XCD L2 locality
    const int f = (blockIdx.x & 7) * 256 + (blockIdx.x >> 3);
    const int t = threadIdx.x;
    const int l = t & 63;
    const int q = l >> 4;
    const int m = l & 15;
    const int base = f * 128 + (t >> 6) * 32;   // wave's 32-pixel span
    const int b    = base >> 16;                // span never crosses b
    const int hwb  = base & (HW_ - 1);
    const int h    = hwb >> 8;                  // same row for both groups
    const int w0   = (hwb & (W_ - 1)) + m;      // group g pixel w = w0+16g

    const float* offp = off + (size_t)b * (2 * KK_ * HW_) + (size_t)h * W_;
    const uint4* ib   = ((const uint4*)wsu) + (size_t)b * HW_ * 2;
    const uint4* kb   = (const uint4*)(wsu + KER_OFF);

    // B-fragments: 5 x 16 B, register-resident
    bf16x8 bfr[NKB];
#pragma unroll
    for (int kbk = 0; kbk < NKB; kbk++) {
        U4S8 cv; cv.u = kb[kbk * 64 + l];
        bfr[kbk] = cv.s;
    }

    // ALL entry loads issued together: 20 offsets + 2 target float4s (nt).
    // tap>8 clamped to 8: valid memory; contribution zeroed by B=0 padding.
    float dyv[2][NKB], dxv[2][NKB];
#pragma unroll
    for (int g = 0; g < 2; g++)
#pragma unroll
        for (int kbk = 0; kbk < NKB; kbk++) {
            const int tap = min(2 * kbk + (q >> 1), KK_ - 1);
            dyv[g][kbk] = __builtin_nontemporal_load(
                &offp[(size_t)(2 * tap) * HW_ + w0 + 16 * g]);
            dxv[g][kbk] = __builtin_nontemporal_load(
                &offp[(size_t)(2 * tap + 1) * HW_ + w0 + 16 * g]);
        }
    // targets (C/D layout: col=lane&15=o, row=4q+reg=pixel-in-group)
    const float* tbase = tgt + (size_t)b * (CO_ * HW_) + (size_t)m * HW_
                       + hwb + 4 * q;
    const f32x4 tv0 = __builtin_nontemporal_load((const f32x4*)(tbase));
    const f32x4 tv1 = __builtin_nontemporal_load((const f32x4*)(tbase + 16));

    f32x4 acc[2] = {{0.f, 0.f, 0.f, 0.f}, {0.f, 0.f, 0.f, 0.f}};
    uint4 cor[2][4];
    float wts[2][4];

    // prologue: group 0, k-block 0 (never a padding block)
    {
        int idx[4];
        tap_setup(h, w0, q >> 1, dyv[0][0], dxv[0][0], idx, wts[0]);
#pragma unroll
        for (int i = 0; i < 4; i++) cor[0][i] = ib[idx[i] * 2 + (q & 1)];
    }

#pragma unroll
    for (int kbi = 0; kbi < 2 * NKB; kbi++) {
        const int cur = kbi & 1, nxt = cur ^ 1;
        if (kbi + 1 < 2 * NKB) {
            const int gn = (kbi + 1) / NKB, kn = (kbi + 1) % NKB;
            int idx[4];
            tap_setup(h, w0 + 16 * gn, min(2 * kn + (q >> 1), KK_ - 1),
                      dyv[gn][kn], dxv[gn][kn], idx, wts[nxt]);
            if (kn == NKB - 1) {
                // K-padding lanes (tap 9): B-frag is 0 there, so collapse
                // their gathers onto record 0 (broadcast, 1-2 cachelines)
                // with wt=0 instead of scattering real clamped-tap-8 gathers.
                const bool pad = (q >> 1) != 0;
                if (pad) {
                    wts[nxt][0] = 0.f; wts[nxt][1] = 0.f;
                    wts[nxt][2] = 0.f; wts[nxt][3] = 0.f;
                    idx[0] = 0; idx[1] = 0; idx[2] = 0; idx[3] = 0;
                }
            }
#pragma unroll
            for (int i = 0; i < 4; i++) cor[nxt][i] = ib[idx[i] * 2 + (q & 1)];
        }

        const int g = kbi / NKB;
        const int kkb = kbi % NKB;
        const float w0_ = wts[cur][0], w1_ = wts[cur][1],
                    w2_ = wts[cur][2], w3_ = wts[cur][3];
        const uint4 c0 = cor[cur][0], c1 = cor[cur][1],
                    c2 = cor[cur][2], c3 = cor[cur][3];
        uint4 A4;
        A4.x = blendpack(c0.x, c1.x, c2.x, c3.x, w0_, w1_, w2_, w3_);
        A4.y = blendpack(c0.y, c1.y, c2.y, c3.y, w0_, w1_, w2_, w3_);
        A4.z = blendpack(c0.z, c1.z, c2.z, c3.z, w0_, w1_, w2_, w3_);
        A4.w = blendpack(c0.w, c1.w, c2.w, c3.w, w0_, w1_, w2_, w3_);
        U4S8 ca; ca.u = A4;

        acc[g] = __builtin_amdgcn_mfma_f32_16x16x32_bf16(ca.s, bfr[kkb],
                                                         acc[g], 0, 0, 0);
    }

    float d0 = acc[0][0] - tv0[0], d1 = acc[0][1] - tv0[1],
          d2 = acc[0][2] - tv0[2], d3 = acc[0][3] - tv0[3];
    float e0 = acc[1][0] - tv1[0], e1 = acc[1][1] - tv1[1],
          e2 = acc[1][2] - tv1[2], e3 = acc[1][3] - tv1[3];
    float part = (d0 * d0 + d1 * d1 + d2 * d2 + d3 * d3
                + e0 * e0 + e1 * e1 + e2 * e2 + e3 * e3)
               * (1.0f / (float)((size_t)B_ * CO_ * HW_));

    // wave reduce -> LDS -> ONE plain store per block (no atomics: 2048
    // same-address atomics serialize into a ~6 us burst tail — measured r2)
#pragma unroll
    for (int sft = 32; sft > 0; sft >>= 1)
        part += __shfl_down(part, sft, 64);

    __shared__ float red[4];
    if (l == 0)
        red[t >> 6] = part;
    __syncthreads();
    if (t == 0)
        partials[blockIdx.x] = red[0] + red[1] + red[2] + red[3];
}

// ------- Kernel 3: sum NBLK block partials -> out --------------------------
__global__ __launch_bounds__(256) void reduce_partials(
    const float* __restrict__ partials, float* __restrict__ out)
{
    const int t = threadIdx.x;
    float s = 0.f;
#pragma unroll
    for (int i = 0; i < NBLK / 256; i++)
        s += partials[t + i * 256];
#pragma unroll
    for (int sft = 32; sft > 0; sft >>= 1)
        s += __shfl_down(s, sft, 64);
    __shared__ float red[4];
    if ((t & 63) == 0) red[t >> 6] = s;
    __syncthreads();
    if (t == 0) out[0] = red[0] + red[1] + red[2] + red[3];
}

// ------- Fallback (round-1 NCHW kernel, used if ws too small) --------------
__global__ __launch_bounds__(256) void deform_loss_kernel(
    const float* __restrict__ off, const float* __restrict__ inp,
    const float* __restrict__ ker, const float* __restrict__ tgt,
    float* __restrict__ out)
{
    const int idx = blockIdx.x * blockDim.x + threadIdx.x;
    float part = 0.f;
    if (idx < B_ * H_ * W_) {
        const int w  = idx & (W_ - 1);
        const int h  = (idx >> 8) & (H_ - 1);
        const int b  = idx >> 16;
        const int hw = h * W_ + w;
        const float* offb = off + (size_t)b * (2 * KK_ * HW_);
        const float* inpb = inp + (size_t)b * (C_ * HW_);
        float acc[CO_];
#pragma unroll
        for (int o = 0; o < CO_; o++) acc[o] = 0.f;
        for (int kk = 0; kk < KK_; kk++) {
            const float dy = offb[(2 * kk)     * HW_ + hw];
            const float dx = offb[(2 * kk + 1) * HW_ + hw];
            const float y = dy + (float)(h - 1 + kk / KS_);
            const float x = dx + (float)(w - 1 + kk % KS_);
            const float y0f = floorf(y);
            const float x0f = floorf(x);
            const int   y0  = (int)y0f;
            const int   x0  = (int)x0f;
            const float wy  = y - y0f;
            const float wx  = x - x0f;
            float w00 = (1.f - wy) * (1.f - wx);
            float w01 = (1.f - wy) * wx;
            float w10 = wy * (1.f - wx);
            float w11 = wy * wx;
            const bool v0y = ((unsigned)y0       < (unsigned)H_);
            const bool v1y = ((unsigned)(y0 + 1) < (unsigned)H_);
            const bool v0x = ((unsigned)x0       < (unsigned)W_);
            const bool v1x = ((unsigned)(x0 + 1) < (unsigned)W_);
            w00 = (v0y & v0x) ? w00 : 0.f;
            w01 = (v0y & v1x) ? w01 : 0.f;
            w10 = (v1y & v0x) ? w10 : 0.f;
            w11 = (v1y & v1x) ? w11 : 0.f;
            const int i00 = min(max(y0,0),H_-1)*W_ + min(max(x0,0),W_-1);
            const int i01 = min(max(y0,0),H_-1)*W_ + min(max(x0+1,0),W_-1);
            const int i10 = min(max(y0+1,0),H_-1)*W_ + min(max(x0,0),W_-1);
            const int i11 = min(max(y0+1,0),H_-1)*W_ + min(max(x0+1,0),W_-1);
            for (int c = 0; c < C_; c++) {
                const float* pp = inpb + c * HW_;
                const float s = pp[i00]*w00 + pp[i01]*w01 + pp[i10]*w10 + pp[i11]*w11;
#pragma unroll
                for (int o = 0; o < CO_; o++)
                    acc[o] = fmaf(s, ker[(o * C_ + c) * KK_ + kk], acc[o]);
            }
        }
        const float* tb = tgt + (size_t)b * (CO_ * HW_);
#pragma unroll
        for (int o = 0; o < CO_; o++) {
            const float d = acc[o] - tb[o * HW_ + hw];
            part = fmaf(d, d, part);
        }
        part *= (1.0f / (float)((size_t)B_ * CO_ * HW_));
    }
#pragma unroll
    for (int sft = 32; sft > 0; sft >>= 1)
        part += __shfl_down(part, sft, 64);
    if ((threadIdx.x & 63) == 0)
        atomicAdd(out, part);
}

extern "C" void kernel_launch(void* const* d_in, const int* in_sizes, int n_in,
                              void* d_out, int out_size, void* d_ws, size_t ws_size,
                              hipStream_t stream) {
    const float* offsets = (const float*)d_in[0];
    const float* input   = (const float*)d_in[1];
    const float* ker     = (const float*)d_in[2];
    const float* target  = (const float*)d_in[3];
    float* out = (float*)d_out;

    const size_t need = (PART_OFF + NBLK) * sizeof(unsigned);
    if (ws_size >= need) {
        unsigned* wsu = (unsigned*)d_ws;
        pack_nhwc_bf16<<<(B_ * HW_) / 256, 256, 0, stream>>>(input, ker, wsu);
        // 2048 blocks x 256 threads: wave = 2 groups x 16 pixels x 4 k-quads
        deform_loss_mfma<<<NBLK, 256, 0, stream>>>(
            offsets, wsu, target, (float*)(wsu + PART_OFF));
        reduce_partials<<<1, 256, 0, stream>>>(
            (const float*)(wsu + PART_OFF), out);
    } else {
        hipMemsetAsync(out, 0, sizeof(float), stream);
        const int total = B_ * H_ * W_;
        deform_loss_kernel<<<(total + 255) / 256, 256, 0, stream>>>(
            offsets, input, ker, target, out);
    }
}

// Round 7
// 112.410 us; speedup vs baseline: 6.0191x; 1.0540x over previous
//
#include <hip/hip_runtime.h>

#define B_  4
#define C_  16
#define H_  256
#define W_  256
#define CO_ 16
#define KS_ 3
#define KK_ 9
#define HW_ (H_ * W_)
// ws layout (u32 words): bf16 NHWC image | kbuf B-frags | partials (float)
#define IMG_WORDS ((size_t)B_ * HW_ * 8)   // 32 B per pixel
#define KER_OFF   IMG_WORDS
#define NKB 5                               // k-blocks per group: K=160
#define NBLK 2048                           // blocks: 128 pixels each
#define PART_OFF (KER_OFF + (size_t)NKB * 256)

typedef __attribute__((ext_vector_type(8))) short bf16x8;
typedef __attribute__((ext_vector_type(4))) float f32x4;
union U4S8 { uint4 u; bf16x8 s; };

#define LOBF(u) __uint_as_float((u) << 16)
#define HIBF(u) __uint_as_float((u) & 0xffff0000u)

__device__ __forceinline__ unsigned rne_bf16(float v) {
    unsigned b = __float_as_uint(v);
    return (b + 0x7fffu + ((b >> 16) & 1u)) >> 16;
}

// ------- Kernel 1: NCHW fp32 -> NHWC bf16 pack + B-fragment kernel pack ----
// Block mapping XCD-aligned with deform_loss_mfma: pack block bx (on XCD
// bx&7) writes exactly the pixel range that deform blocks on the same XCD
// will gather -> image stays dirty-resident in the LOCAL per-XCD L2.
// NOTE: plain loads everywhere — nontemporal hints regressed (r6: inputs are
// L3-resident across iterations; nt forced cold-read behavior).
__global__ __launch_bounds__(256) void pack_nhwc_bf16(
    const float* __restrict__ inp, const float* __restrict__ ker,
    unsigned* __restrict__ wsu)
{
    const int t = threadIdx.x;
    // bijection on [0,1024): XCD x=bx&7 covers 256-px chunks [x*128,(x+1)*128)
    const int j = (blockIdx.x & 7) * 128 + (blockIdx.x >> 3);
    const int e = j * 256 + t;              // flat pixel (b*HW + hw)
    const int b = e >> 16;
    const int hw = e & (HW_ - 1);
    const float* src = inp + (size_t)b * (C_ * HW_) + hw;
    float v[C_];
#pragma unroll
    for (int c = 0; c < C_; c++)
        v[c] = src[c * HW_];                // coalesced per c-plane
    unsigned u[8];
#pragma unroll
    for (int j2 = 0; j2 < 8; j2++)
        u[j2] = rne_bf16(v[2 * j2]) | (rne_bf16(v[2 * j2 + 1]) << 16);
    uint4* dst = ((uint4*)wsu) + (size_t)e * 2;   // 32 B per pixel
    dst[0] = make_uint4(u[0], u[1], u[2], u[3]);
    dst[1] = make_uint4(u[4], u[5], u[6], u[7]);

    if (blockIdx.x == 0) {
        // kbuf: B-fragment layout for mfma_f32_16x16x32_bf16.
        //   B[k][n]: k = (lane>>4)*8 + j, n = o = lane&15,
        //   tap = 2*blk + (k>>4), c = k&15; zero when tap > 8 (K padding).
        for (int i = t; i < NKB * 256; i += 256) {
            const int wj  = i & 3;
            const int l   = (i >> 2) & 63;
            const int blk = i >> 8;
            const int o   = l & 15;
            unsigned lo = 0, hi = 0;
            {
                int jj = 2 * wj, k = (l >> 4) * 8 + jj;
                int tap = 2 * blk + (k >> 4), c = k & 15;
                if (tap <= 8) lo = rne_bf16(ker[(o * C_ + c) * KK_ + tap]);
                jj = 2 * wj + 1; k = (l >> 4) * 8 + jj;
                tap = 2 * blk + (k >> 4); c = k & 15;
                if (tap <= 8) hi = rne_bf16(ker[(o * C_ + c) * KK_ + tap]);
            }
            wsu[KER_OFF + i] = lo | (hi << 16);
        }
    }
}

// ------- tap address/weight setup ------------------------------------------
__device__ __forceinline__ void tap_setup(
    int h, int w, int kk, float dy, float dx,
    int* idx, float* wt)
{
    const float y = dy + (float)(h - 1 + kk / KS_);
    const float x = dx + (float)(w - 1 + kk % KS_);
    const float y0f = floorf(y);
    const float x0f = floorf(x);
    const int   y0  = (int)y0f;
    const int   x0  = (int)x0f;
    const float wy  = y - y0f;
    const float wx  = x - x0f;

    float w00 = (1.f - wy) * (1.f - wx);
    float w01 = (1.f - wy) * wx;
    float w10 = wy * (1.f - wx);
    float w11 = wy * wx;

    const bool v0y = ((unsigned)y0       < (unsigned)H_);
    const bool v1y = ((unsigned)(y0 + 1) < (unsigned)H_);
    const bool v0x = ((unsigned)x0       < (unsigned)W_);
    const bool v1x = ((unsigned)(x0 + 1) < (unsigned)W_);

    wt[0] = (v0y & v0x) ? w00 : 0.f;
    wt[1] = (v0y & v1x) ? w01 : 0.f;
    wt[2] = (v1y & v0x) ? w10 : 0.f;
    wt[3] = (v1y & v1x) ? w11 : 0.f;

    const int y0c = min(max(y0,     0), H_ - 1);
    const int y1c = min(max(y0 + 1, 0), H_ - 1);
    const int x0c = min(max(x0,     0), W_ - 1);
    const int x1c = min(max(x0 + 1, 0), W_ - 1);

    idx[0] = y0c * W_ + x0c;
    idx[1] = y0c * W_ + x1c;
    idx[2] = y1c * W_ + x0c;
    idx[3] = y1c * W_ + x1c;
}

// blend + truncation-pack to bf16 pair: two independent scalar fma chains
// + one v_perm_b32 (the f32x2/v_pk_fma variant regressed: VOP3P needs
// aligned VGPR pairs -> 8 marshalling movs per call).
__device__ __forceinline__ unsigned blendpack(
    unsigned a, unsigned b, unsigned c, unsigned d,
    float w0, float w1, float w2, float w3)
{
    const float lo = w0 * LOBF(a) + w1 * LOBF(b) + w2 * LOBF(c) + w3 * LOBF(d);
    const float hi = w0 * HIBF(a) + w1 * HIBF(b) + w2 * HIBF(c) + w3 * HIBF(d);
    // result = [hi:31-16 | lo:31-16]  (bytes a3,a2,b3,b2)
    return __builtin_amdgcn_perm(__float_as_uint(hi), __float_as_uint(lo),
                                 0x07060302u);
}

// ------- Kernel 2: deform-conv + MSE via MFMA, 2 groups/wave, no atomics ---
// Wave = 2 groups x 16 pixels x 4 k-quads. Lane(q=l>>4, m=l&15) holds
// k = q*8+j -> one 16B half of a bf16 NHWC record. 5 MFMAs per group.
// Gathers are PREFETCHED 2 ITERATIONS AHEAD (3-slot rotation): the kernel is
// latency-bound (r4: MfmaUtil 1%, VALU 31%, Occ 31%), and 1-iter distance
// (~200 issue-cy) did not cover the ~200-600 cy L2/L3 gather latency. The
// compiler won't hoist further on its own (it caps at the 64-VGPR occupancy
// boundary) — the explicit 3rd slot forces the deeper pipeline.
__global__ __launch_bounds__(256) void deform_loss_mfma(
    const float* __restrict__ off, const unsigned* __restrict__ wsu,
    const float* __restrict__ tgt, float* __restrict__ partials)
{
    // XCD swizzle: bijection on [0,2048); xcd = blk&7 covers 256 consecutive
    // 128-pixel blocks = 128 contiguous rows -> per-XCD L2 locality
    const int f = (blockIdx.x & 7) * 256 + (blockIdx.x >> 3);
    const int t = threadIdx.x;
    const int l = t & 63;
    const int q = l >> 4;
    const int m = l & 15;
    const int base = f * 128 + (t >> 6) * 32;   // wave's 32-pixel span
    const int b    = base >> 16;                // span never crosses b
    const int hwb  = base & (HW_ - 1);
    const int h    = hwb >> 8;                  // same row for both groups
    const int w0   = (hwb & (W_ - 1)) + m;      // group g pixel w = w0+16g

    const float* offp = off + (size_t)b * (2 * KK_ * HW_) + (size_t)h * W_;
    const uint4* ib   = ((const uint4*)wsu) + (size_t)b * HW_ * 2;
    const uint4* kb   = (const uint4*)(wsu + KER_OFF);

    // B-fragments: 5 x 16 B, register-resident
    bf16x8 bfr[NKB];
#pragma unroll
    for (int kbk = 0; kbk < NKB; kbk++) {
        U4S8 cv; cv.u = kb[kbk * 64 + l];
        bfr[kbk] = cv.s;
    }

    // ALL entry loads issued together: 20 offsets + 2 target float4s.
    // tap>8 clamped to 8: valid memory; contribution zeroed by B=0 padding.
    float dyv[2][NKB], dxv[2][NKB];
#pragma unroll
    for (int g = 0; g < 2; g++)
#pragma unroll
        for (int kbk = 0; kbk < NKB; kbk++) {
            const int tap = min(2 * kbk + (q >> 1), KK_ - 1);
            dyv[g][kbk] = offp[(size_t)(2 * tap) * HW_ + w0 + 16 * g];
            dxv[g][kbk] = offp[(size_t)(2 * tap + 1) * HW_ + w0 + 16 * g];
        }
    // targets (C/D layout: col=lane&15=o, row=4q+reg=pixel-in-group)
    const float* tbase = tgt + (size_t)b * (CO_ * HW_) + (size_t)m * HW_
                       + hwb + 4 * q;
    const float4 tv0 = *(const float4*)(tbase);
    const float4 tv1 = *(const float4*)(tbase + 16);

    f32x4 acc[2] = {{0.f, 0.f, 0.f, 0.f}, {0.f, 0.f, 0.f, 0.f}};
    uint4 cor[3][4];
    float wts[3][4];

    // PREP(KBI, SLOT): tap_setup + pad-collapse + issue 4 corner gathers.
    // K-padding lanes (tap 9, kn==NKB-1 && q>=2): B-frag is 0, so collapse
    // their gathers onto record 0 (broadcast) with wt=0 instead of
    // scattering real clamped-tap-8 gathers.
#define PREP(KBI, SLOT) do {                                               \
        const int gn_ = (KBI) / NKB, kn_ = (KBI) % NKB;                    \
        int idx_[4];                                                       \
        tap_setup(h, w0 + 16 * gn_, min(2 * kn_ + (q >> 1), KK_ - 1),      \
                  dyv[gn_][kn_], dxv[gn_][kn_], idx_, wts[SLOT]);          \
        if (kn_ == NKB - 1 && (q >> 1) != 0) {                             \
            wts[SLOT][0] = 0.f; wts[SLOT][1] = 0.f;                        \
            wts[SLOT][2] = 0.f; wts[SLOT][3] = 0.f;                        \
            idx_[0] = 0; idx_[1] = 0; idx_[2] = 0; idx_[3] = 0;            \
        }                                                                  \
        _Pragma("unroll")                                                  \
        for (int i_ = 0; i_ < 4; i_++)                                     \
            cor[SLOT][i_] = ib[idx_[i_] * 2 + (q & 1)];                    \
    } while (0)

    // prologue: fill slots 0 and 1 (kbi = 0, 1 — never padding blocks)
    PREP(0, 0);
    PREP(1, 1);

#pragma unroll
    for (int kbi = 0; kbi < 2 * NKB; kbi++) {
        const int cur = kbi % 3;
        if (kbi + 2 < 2 * NKB)
            PREP(kbi + 2, (kbi + 2) % 3);

        const int g = kbi / NKB;
        const int kkb = kbi % NKB;
        const float w0_ = wts[cur][0], w1_ = wts[cur][1],
                    w2_ = wts[cur][2], w3_ = wts[cur][3];
        const uint4 c0 = cor[cur][0], c1 = cor[cur][1],
                    c2 = cor[cur][2], c3 = cor[cur][3];
        uint4 A4;
        A4.x = blendpack(c0.x, c1.x, c2.x, c3.x, w0_, w1_, w2_, w3_);
        A4.y = blendpack(c0.y, c1.y, c2.y, c3.y, w0_, w1_, w2_, w3_);
        A4.z = blendpack(c0.z, c1.z, c2.z, c3.z, w0_, w1_, w2_, w3_);
        A4.w = blendpack(c0.w, c1.w, c2.w, c3.w, w0_, w1_, w2_, w3_);
        U4S8 ca; ca.u = A4;

        acc[g] = __builtin_amdgcn_mfma_f32_16x16x32_bf16(ca.s, bfr[kkb],
                                                         acc[g], 0, 0, 0);
    }
#undef PREP

    float d0 = acc[0][0] - tv0.x, d1 = acc[0][1] - tv0.y,
          d2 = acc[0][2] - tv0.z, d3 = acc[0][3] - tv0.w;
    float e0 = acc[1][0] - tv1.x, e1 = acc[1][1] - tv1.y,
          e2 = acc[1][2] - tv1.z, e3 = acc[1][3] - tv1.w;
    float part = (d0 * d0 + d1 * d1 + d2 * d2 + d3 * d3
                + e0 * e0 + e1 * e1 + e2 * e2 + e3 * e3)
               * (1.0f / (float)((size_t)B_ * CO_ * HW_));

    // wave reduce -> LDS -> ONE plain store per block (no atomics: 2048
    // same-address atomics serialize into a ~6 us burst tail — measured r2)
#pragma unroll
    for (int sft = 32; sft > 0; sft >>= 1)
        part += __shfl_down(part, sft, 64);

    __shared__ float red[4];
    if (l == 0)
        red[t >> 6] = part;
    __syncthreads();
    if (t == 0)
        partials[blockIdx.x] = red[0] + red[1] + red[2] + red[3];
}

// ------- Kernel 3: sum NBLK block partials -> out --------------------------
__global__ __launch_bounds__(256) void reduce_partials(
    const float* __restrict__ partials, float* __restrict__ out)
{
    const int t = threadIdx.x;
    float s = 0.f;
#pragma unroll
    for (int i = 0; i < NBLK / 256; i++)
        s += partials[t + i * 256];
#pragma unroll
    for (int sft = 32; sft > 0; sft >>= 1)
        s += __shfl_down(s, sft, 64);
    __shared__ float red[4];
    if ((t & 63) == 0) red[t >> 6] = s;
    __syncthreads();
    if (t == 0) out[0] = red[0] + red[1] + red[2] + red[3];
}

// ------- Fallback (round-1 NCHW kernel, used if ws too small) --------------
__global__ __launch_bounds__(256) void deform_loss_kernel(
    const float* __restrict__ off, const float* __restrict__ inp,
    const float* __restrict__ ker, const float* __restrict__ tgt,
    float* __restrict__ out)
{
    const int idx = blockIdx.x * blockDim.x + threadIdx.x;
    float part = 0.f;
    if (idx < B_ * H_ * W_) {
        const int w  = idx & (W_ - 1);
        const int h  = (idx >> 8) & (H_ - 1);
        const int b  = idx >> 16;
        const int hw = h * W_ + w;
        const float* offb = off + (size_t)b * (2 * KK_ * HW_);
        const float* inpb = inp + (size_t)b * (C_ * HW_);
        float acc[CO_];
#pragma unroll
        for (int o = 0; o < CO_; o++) acc[o] = 0.f;
        for (int kk = 0; kk < KK_; kk++) {
            const float dy = offb[(2 * kk)     * HW_ + hw];
            const float dx = offb[(2 * kk + 1) * HW_ + hw];
            const float y = dy + (float)(h - 1 + kk / KS_);
            const float x = dx + (float)(w - 1 + kk % KS_);
            const float y0f = floorf(y);
            const float x0f = floorf(x);
            const int   y0  = (int)y0f;
            const int   x0  = (int)x0f;
            const float wy  = y - y0f;
            const float wx  = x - x0f;
            float w00 = (1.f - wy) * (1.f - wx);
            float w01 = (1.f - wy) * wx;
            float w10 = wy * (1.f - wx);
            float w11 = wy * wx;
            const bool v0y = ((unsigned)y0       < (unsigned)H_);
            const bool v1y = ((unsigned)(y0 + 1) < (unsigned)H_);
            const bool v0x = ((unsigned)x0       < (unsigned)W_);
            const bool v1x = ((unsigned)(x0 + 1) < (unsigned)W_);
            w00 = (v0y & v0x) ? w00 : 0.f;
            w01 = (v0y & v1x) ? w01 : 0.f;
            w10 = (v1y & v0x) ? w10 : 0.f;
            w11 = (v1y & v1x) ? w11 : 0.f;
            const int i00 = min(max(y0,0),H_-1)*W_ + min(max(x0,0),W_-1);
            const int i01 = min(max(y0,0),H_-1)*W_ + min(max(x0+1,0),W_-1);
            const int i10 = min(max(y0+1,0),H_-1)*W_ + min(max(x0,0),W_-1);
            const int i11 = min(max(y0+1,0),H_-1)*W_ + min(max(x0+1,0),W_-1);
            for (int c = 0; c < C_; c++) {
                const float* pp = inpb + c * HW_;
                const float s = pp[i00]*w00 + pp[i01]*w01 + pp[i10]*w10 + pp[i11]*w11;
#pragma unroll
                for (int o = 0; o < CO_; o++)
                    acc[o] = fmaf(s, ker[(o * C_ + c) * KK_ + kk], acc[o]);
            }
        }
        const float* tb = tgt + (size_t)b * (CO_ * HW_);
#pragma unroll
        for (int o = 0; o < CO_; o++) {
            const float d = acc[o] - tb[o * HW_ + hw];
            part = fmaf(d, d, part);
        }
        part *= (1.0f / (float)((size_t)B_ * CO_ * HW_));
    }
#pragma unroll
    for (int sft = 32; sft > 0; sft >>= 1)
        part += __shfl_down(part, sft, 64);
    if ((threadIdx.x & 63) == 0)
        atomicAdd(out, part);
}

extern "C" void kernel_launch(void* const* d_in, const int* in_sizes, int n_in,
                              void* d_out, int out_size, void* d_ws, size_t ws_size,
                              hipStream_t stream) {
    const float* offsets = (const float*)d_in[0];
    const float* input   = (const float*)d_in[1];
    const float* ker     = (const float*)d_in[2];
    const float* target  = (const float*)d_in[3];
    float* out = (float*)d_out;

    const size_t need = (PART_OFF + NBLK) * sizeof(unsigned);
    if (ws_size >= need) {
        unsigned* wsu = (unsigned*)d_ws;
        pack_nhwc_bf16<<<(B_ * HW_) / 256, 256, 0, stream>>>(input, ker, wsu);
        // 2048 blocks x 256 threads: wave = 2 groups x 16 pixels x 4 k-quads
        deform_loss_mfma<<<NBLK, 256, 0, stream>>>(
            offsets, wsu, target, (float*)(wsu + PART_OFF));
        reduce_partials<<<1, 256, 0, stream>>>(
            (const float*)(wsu + PART_OFF), out);
    } else {
        hipMemsetAsync(out, 0, sizeof(float), stream);
        const int total = B_ * H_ * W_;
        deform_loss_kernel<<<(total + 255) / 256, 256, 0, stream>>>(
            offsets, input, ker, target, out);
    }
}

// Round 9
// 111.243 us; speedup vs baseline: 6.0823x; 1.0105x over previous
//
#include <hip/hip_runtime.h>
#include <hip/hip_fp16.h>

#define B_  4
#define C_  16
#define H_  256
#define W_  256
#define CO_ 16
#define KS_ 3
#define KK_ 9
#define HW_ (H_ * W_)
// ws layout (u32 words): f16 NHWC image | kbuf B-frags | partials (float)
#define IMG_WORDS ((size_t)B_ * HW_ * 8)   // 32 B per pixel
#define KER_OFF   IMG_WORDS
#define NKB 5                               // k-blocks per group: K=160
#define NBLK 2048                           // blocks: 128 pixels each
#define PART_OFF (KER_OFF + (size_t)NKB * 256)

typedef _Float16 f16x8 __attribute__((ext_vector_type(8)));
typedef __attribute__((ext_vector_type(4))) float f32x4;
union U4H8 { uint4 u; f16x8 h; };
union UH2  { unsigned u; __half2 h; };

// ------- Kernel 1: NCHW fp32 -> NHWC f16 pack + B-fragment kernel pack -----
// Block mapping XCD-aligned with deform_loss_mfma: pack block bx (on XCD
// bx&7) writes exactly the pixel range that deform blocks on the same XCD
// will gather -> image stays dirty-resident in the LOCAL per-XCD L2.
// f16 (not bf16): deform blends with v_pk_fma_f16 (2 ch/op, single-VGPR
// packed — unlike pk_f32 which needs aligned pairs, r1 lesson). Precision
// is better too (10-bit vs 8-bit mantissa; range ample for N(0,1) data).
__global__ __launch_bounds__(256) void pack_nhwc_f16(
    const float* __restrict__ inp, const float* __restrict__ ker,
    unsigned* __restrict__ wsu)
{
    const int t = threadIdx.x;
    // bijection on [0,1024): XCD x=bx&7 covers 256-px chunks [x*128,(x+1)*128)
    const int j = (blockIdx.x & 7) * 128 + (blockIdx.x >> 3);
    const int e = j * 256 + t;              // flat pixel (b*HW + hw)
    const int b = e >> 16;
    const int hw = e & (HW_ - 1);
    const float* src = inp + (size_t)b * (C_ * HW_) + hw;
    float v[C_];
#pragma unroll
    for (int c = 0; c < C_; c++)
        v[c] = src[c * HW_];                // coalesced per c-plane
    unsigned u[8];
#pragma unroll
    for (int j2 = 0; j2 < 8; j2++) {
        UH2 p; p.h = __floats2half2_rn(v[2 * j2], v[2 * j2 + 1]);
        u[j2] = p.u;
    }
    uint4* dst = ((uint4*)wsu) + (size_t)e * 2;   // 32 B per pixel
    dst[0] = make_uint4(u[0], u[1], u[2], u[3]);
    dst[1] = make_uint4(u[4], u[5], u[6], u[7]);

    if (blockIdx.x == 0) {
        // kbuf: B-fragment layout for mfma_f32_16x16x32_f16.
        //   B[k][n]: k = (lane>>4)*8 + j, n = o = lane&15,
        //   tap = 2*blk + (k>>4), c = k&15; zero when tap > 8 (K padding).
        for (int i = t; i < NKB * 256; i += 256) {
            const int wj  = i & 3;
            const int l   = (i >> 2) & 63;
            const int blk = i >> 8;
            const int o   = l & 15;
            unsigned lo = 0, hi = 0;
            {
                int jj = 2 * wj, k = (l >> 4) * 8 + jj;
                int tap = 2 * blk + (k >> 4), c = k & 15;
                if (tap <= 8) {
                    __half hh = __float2half(ker[(o * C_ + c) * KK_ + tap]);
                    lo = __half_as_ushort(hh);
                }
                jj = 2 * wj + 1; k = (l >> 4) * 8 + jj;
                tap = 2 * blk + (k >> 4); c = k & 15;
                if (tap <= 8) {
                    __half hh = __float2half(ker[(o * C_ + c) * KK_ + tap]);
                    hi = __half_as_ushort(hh);
                }
            }
            wsu[KER_OFF + i] = lo | (hi << 16);
        }
    }
}

// ------- tap address/weight setup ------------------------------------------
__device__ __forceinline__ void tap_setup(
    int h, int w, int kk, float dy, float dx,
    int* idx, float* wt)
{
    const float y = dy + (float)(h - 1 + kk / KS_);
    const float x = dx + (float)(w - 1 + kk % KS_);
    const float y0f = floorf(y);
    const float x0f = floorf(x);
    const int   y0  = (int)y0f;
    const int   x0  = (int)x0f;
    const float wy  = y - y0f;
    const float wx  = x - x0f;

    float w00 = (1.f - wy) * (1.f - wx);
    float w01 = (1.f - wy) * wx;
    float w10 = wy * (1.f - wx);
    float w11 = wy * wx;

    const bool v0y = ((unsigned)y0       < (unsigned)H_);
    const bool v1y = ((unsigned)(y0 + 1) < (unsigned)H_);
    const bool v0x = ((unsigned)x0       < (unsigned)W_);
    const bool v1x = ((unsigned)(x0 + 1) < (unsigned)W_);

    wt[0] = (v0y & v0x) ? w00 : 0.f;
    wt[1] = (v0y & v1x) ? w01 : 0.f;
    wt[2] = (v1y & v0x) ? w10 : 0.f;
    wt[3] = (v1y & v1x) ? w11 : 0.f;

    const int y0c = min(max(y0,     0), H_ - 1);
    const int y1c = min(max(y0 + 1, 0), H_ - 1);
    const int x0c = min(max(x0,     0), W_ - 1);
    const int x1c = min(max(x0 + 1, 0), W_ - 1);

    idx[0] = y0c * W_ + x0c;
    idx[1] = y0c * W_ + x1c;
    idx[2] = y1c * W_ + x0c;
    idx[3] = y1c * W_ + x1c;
}

// f16 packed blend: one word = 2 channels; 1 pk_mul + 3 pk_fma, no
// extract/pack ops (vs 17 ops for the bf16 scalar blend+perm).
__device__ __forceinline__ unsigned blendpack_h(
    unsigned a, unsigned b, unsigned c, unsigned d,
    __half2 w0, __half2 w1, __half2 w2, __half2 w3)
{
    UH2 ua, ub, uc, ud, r;
    ua.u = a; ub.u = b; uc.u = c; ud.u = d;
    r.h = __hmul2(ua.h, w0);
    r.h = __hfma2(ub.h, w1, r.h);
    r.h = __hfma2(uc.h, w2, r.h);
    r.h = __hfma2(ud.h, w3, r.h);
    return r.u;
}

// ------- Kernel 2: deform-conv + MSE via MFMA, 2 groups/wave, no atomics ---
// Wave = 2 groups x 16 pixels x 4 k-quads. Lane(q=l>>4, m=l&15) holds
// k = q*8+j -> one 16B half of a f16 NHWC record. 5 MFMAs per group.
// Gathers PREFETCHED 2 ITERATIONS AHEAD (3-slot rotation, r7 win).
__global__ __launch_bounds__(256) void deform_loss_mfma(
    const float* __restrict__ off, const unsigned* __restrict__ wsu,
    const float* __restrict__ tgt, float* __restrict__ partials)
{
    // XCD swizzle: bijection on [0,2048); xcd = blk&7 covers 256 consecutive
    // 128-pixel blocks = 128 contiguous rows -> per-XCD L2 locality
    const int f = (blockIdx.x & 7) * 256 + (blockIdx.x >> 3);
    const int t = threadIdx.x;
    const int l = t & 63;
    const int q = l >> 4;
    const int m = l & 15;
    const int base = f * 128 + (t >> 6) * 32;   // wave's 32-pixel span
    const int b    = base >> 16;                // span never crosses b
    const int hwb  = base & (HW_ - 1);
    const int h    = hwb >> 8;                  // same row for both groups
    const int w0   = (hwb & (W_ - 1)) + m;      // group g pixel w = w0+16g

    const float* offp = off + (size_t)b * (2 * KK_ * HW_) + (size_t)h * W_;
    const uint4* ib   = ((const uint4*)wsu) + (size_t)b * HW_ * 2;
    const uint4* kb   = (const uint4*)(wsu + KER_OFF);

    // B-fragments: 5 x 16 B, register-resident
    f16x8 bfr[NKB];
#pragma unroll
    for (int kbk = 0; kbk < NKB; kbk++) {
        U4H8 cv; cv.u = kb[kbk * 64 + l];
        bfr[kbk] = cv.h;
    }

    // ALL entry loads issued together: 20 offsets + 2 target float4s.
    // tap>8 clamped to 8: valid memory; contribution zeroed by B=0 padding.
    float dyv[2][NKB], dxv[2][NKB];
#pragma unroll
    for (int g = 0; g < 2; g++)
#pragma unroll
        for (int kbk = 0; kbk < NKB; kbk++) {
            const int tap = min(2 * kbk + (q >> 1), KK_ - 1);
            dyv[g][kbk] = offp[(size_t)(2 * tap) * HW_ + w0 + 16 * g];
            dxv[g][kbk] = offp[(size_t)(2 * tap + 1) * HW_ + w0 + 16 * g];
        }
    // targets (C/D layout: col=lane&15=o, row=4q+reg=pixel-in-group)
    const float* tbase = tgt + (size_t)b * (CO_ * HW_) + (size_t)m * HW_
                       + hwb + 4 * q;
    const float4 tv0 = *(const float4*)(tbase);
    const float4 tv1 = *(const float4*)(tbase + 16);

    f32x4 acc[2] = {{0.f, 0.f, 0.f, 0.f}, {0.f, 0.f, 0.f, 0.f}};
    uint4 cor[3][4];
    float wts[3][4];

    // PREP(KBI, SLOT): tap_setup + pad-collapse + issue 4 corner gathers.
    // K-padding lanes (tap 9, kn==NKB-1 && q>=2): B-frag is 0, so collapse
    // their gathers onto record 0 (broadcast) with wt=0 instead of
    // scattering real clamped-tap-8 gathers.
#define PREP(KBI, SLOT) do {                                               \
        const int gn_ = (KBI) / NKB, kn_ = (KBI) % NKB;                    \
        int idx_[4];                                                       \
        tap_setup(h, w0 + 16 * gn_, min(2 * kn_ + (q >> 1), KK_ - 1),      \
                  dyv[gn_][kn_], dxv[gn_][kn_], idx_, wts[SLOT]);          \
        if (kn_ == NKB - 1 && (q >> 1) != 0) {                             \
            wts[SLOT][0] = 0.f; wts[SLOT][1] = 0.f;                        \
            wts[SLOT][2] = 0.f; wts[SLOT][3] = 0.f;                        \
            idx_[0] = 0; idx_[1] = 0; idx_[2] = 0; idx_[3] = 0;            \
        }                                                                  \
        _Pragma("unroll")                                                  \
        for (int i_ = 0; i_ < 4; i_++)                                     \
            cor[SLOT][i_] = ib[idx_[i_] * 2 + (q & 1)];                    \
    } while (0)

    // prologue: fill slots 0 and 1 (kbi = 0, 1 — never padding blocks)
    PREP(0, 0);
    PREP(1, 1);

#pragma unroll
    for (int kbi = 0; kbi < 2 * NKB; kbi++) {
        const int cur = kbi % 3;
        if (kbi + 2 < 2 * NKB)
            PREP(kbi + 2, (kbi + 2) % 3);

        const int g = kbi / NKB;
        const int kkb = kbi % NKB;
        const __half2 w0h = __float2half2_rn(wts[cur][0]);
        const __half2 w1h = __float2half2_rn(wts[cur][1]);
        const __half2 w2h = __float2half2_rn(wts[cur][2]);
        const __half2 w3h = __float2half2_rn(wts[cur][3]);
        const uint4 c0 = cor[cur][0], c1 = cor[cur][1],
                    c2 = cor[cur][2], c3 = cor[cur][3];
        uint4 A4;
        A4.x = blendpack_h(c0.x, c1.x, c2.x, c3.x, w0h, w1h, w2h, w3h);
        A4.y = blendpack_h(c0.y, c1.y, c2.y, c3.y, w0h, w1h, w2h, w3h);
        A4.z = blendpack_h(c0.z, c1.z, c2.z, c3.z, w0h, w1h, w2h, w3h);
        A4.w = blendpack_h(c0.w, c1.w, c2.w, c3.w, w0h, w1h, w2h, w3h);
        U4H8 ca; ca.u = A4;

        acc[g] = __builtin_amdgcn_mfma_f32_16x16x32_f16(ca.h, bfr[kkb],
                                                        acc[g], 0, 0, 0);
    }
#undef PREP

    float d0 = acc[0][0] - tv0.x, d1 = acc[0][1] - tv0.y,
          d2 = acc[0][2] - tv0.z, d3 = acc[0][3] - tv0.w;
    float e0 = acc[1][0] - tv1.x, e1 = acc[1][1] - tv1.y,
          e2 = acc[1][2] - tv1.z, e3 = acc[1][3] - tv1.w;
    float part = (d0 * d0 + d1 * d1 + d2 * d2 + d3 * d3
                + e0 * e0 + e1 * e1 + e2 * e2 + e3 * e3)
               * (1.0f / (float)((size_t)B_ * CO_ * HW_));

    // wave reduce -> LDS -> ONE plain store per block (no atomics: grid is
    // exactly 1 round/CU so all 2048 blocks finish together; same-address
    // atomics serialize into a ~6 us burst tail — measured r2)
#pragma unroll
    for (int sft = 32; sft > 0; sft >>= 1)
        part += __shfl_down(part, sft, 64);

    __shared__ float red[4];
    if (l == 0)
        red[t >> 6] = part;
    __syncthreads();
    if (t == 0)
        partials[blockIdx.x] = red[0] + red[1] + red[2] + red[3];
}

// ------- Kernel 3: sum NBLK block partials -> out --------------------------
__global__ __launch_bounds__(256) void reduce_partials(
    const float* __restrict__ partials, float* __restrict__ out)
{
    const int t = threadIdx.x;
    float s = 0.f;
#pragma unroll
    for (int i = 0; i < NBLK / 256; i++)
        s += partials[t + i * 256];
#pragma unroll
    for (int sft = 32; sft > 0; sft >>= 1)
        s += __shfl_down(s, sft, 64);
    __shared__ float red[4];
    if ((t & 63) == 0) red[t >> 6] = s;
    __syncthreads();
    if (t == 0) out[0] = red[0] + red[1] + red[2] + red[3];
}

// ------- Fallback (round-1 NCHW kernel, used if ws too small) --------------
__global__ __launch_bounds__(256) void deform_loss_kernel(
    const float* __restrict__ off, const float* __restrict__ inp,
    const float* __restrict__ ker, const float* __restrict__ tgt,
    float* __restrict__ out)
{
    const int idx = blockIdx.x * blockDim.x + threadIdx.x;
    float part = 0.f;
    if (idx < B_ * H_ * W_) {
        const int w  = idx & (W_ - 1);
        const int h  = (idx >> 8) & (H_ - 1);
        const int b  = idx >> 16;
        const int hw = h * W_ + w;
        const float* offb = off + (size_t)b * (2 * KK_ * HW_);
        const float* inpb = inp + (size_t)b * (C_ * HW_);
        float acc[CO_];
#pragma unroll
        for (int o = 0; o < CO_; o++) acc[o] = 0.f;
        for (int kk = 0; kk < KK_; kk++) {
            const float dy = offb[(2 * kk)     * HW_ + hw];
            const float dx = offb[(2 * kk + 1) * HW_ + hw];
            const float y = dy + (float)(h - 1 + kk / KS_);
            const float x = dx + (float)(w - 1 + kk % KS_);
            const float y0f = floorf(y);
            const float x0f = floorf(x);
            const int   y0  = (int)y0f;
            const int   x0  = (int)x0f;
            const float wy  = y - y0f;
            const float wx  = x - x0f;
            float w00 = (1.f - wy) * (1.f - wx);
            float w01 = (1.f - wy) * wx;
            float w10 = wy * (1.f - wx);
            float w11 = wy * wx;
            const bool v0y = ((unsigned)y0       < (unsigned)H_);
            const bool v1y = ((unsigned)(y0 + 1) < (unsigned)H_);
            const bool v0x = ((unsigned)x0       < (unsigned)W_);
            const bool v1x = ((unsigned)(x0 + 1) < (unsigned)W_);
            w00 = (v0y & v0x) ? w00 : 0.f;
            w01 = (v0y & v1x) ? w01 : 0.f;
            w10 = (v1y & v0x) ? w10 : 0.f;
            w11 = (v1y & v1x) ? w11 : 0.f;
            const int i00 = min(max(y0,0),H_-1)*W_ + min(max(x0,0),W_-1);
            const int i01 = min(max(y0,0),H_-1)*W_ + min(max(x0+1,0),W_-1);
            const int i10 = min(max(y0+1,0),H_-1)*W_ + min(max(x0,0),W_-1);
            const int i11 = min(max(y0+1,0),H_-1)*W_ + min(max(x0+1,0),W_-1);
            for (int c = 0; c < C_; c++) {
                const float* pp = inpb + c * HW_;
                const float s = pp[i00]*w00 + pp[i01]*w01 + pp[i10]*w10 + pp[i11]*w11;
#pragma unroll
                for (int o = 0; o < CO_; o++)
                    acc[o] = fmaf(s, ker[(o * C_ + c) * KK_ + kk], acc[o]);
            }
        }
        const float* tb = tgt + (size_t)b * (CO_ * HW_);
#pragma unroll
        for (int o = 0; o < CO_; o++) {
            const float d = acc[o] - tb[o * HW_ + hw];
            part = fmaf(d, d, part);
        }
        part *= (1.0f / (float)((size_t)B_ * CO_ * HW_));
    }
#pragma unroll
    for (int sft = 32; sft > 0; sft >>= 1)
        part += __shfl_down(part, sft, 64);
    if ((threadIdx.x & 63) == 0)
        atomicAdd(out, part);
}

extern "C" void kernel_launch(void* const* d_in, const int* in_sizes, int n_in,
                              void* d_out, int out_size, void* d_ws, size_t ws_size,
                              hipStream_t stream) {
    const float* offsets = (const float*)d_in[0];
    const float* input   = (const float*)d_in[1];
    const float* ker     = (const float*)d_in[2];
    const float* target  = (const float*)d_in[3];
    float* out = (float*)d_out;

    const size_t need = (PART_OFF + NBLK) * sizeof(unsigned);
    if (ws_size >= need) {
        unsigned* wsu = (unsigned*)d_ws;
        pack_nhwc_f16<<<(B_ * HW_) / 256, 256, 0, stream>>>(input, ker, wsu);
        // 2048 blocks x 256 threads: wave = 2 groups x 16 pixels x 4 k-quads
        deform_loss_mfma<<<NBLK, 256, 0, stream>>>(
            offsets, wsu, target, (float*)(wsu + PART_OFF));
        reduce_partials<<<1, 256, 0, stream>>>(
            (const float*)(wsu + PART_OFF), out);
    } else {
        hipMemsetAsync(out, 0, sizeof(float), stream);
        const int total = B_ * H_ * W_;
        deform_loss_kernel<<<(total + 255) / 256, 256, 0, stream>>>(
            offsets, input, ker, target, out);
    }
}